// Round 6
// baseline (257.783 us; speedup 1.0000x reference)
//
#include <hip/hip_runtime.h>

#define NCLS 19
#define HWPIX (512 * 512)
#define NB 8
#define PB 256                 // blocks per image
#define NITER 4                // pixels per thread
#define NCOPY 64               // LDS histogram copies (bank-conflict-free)
#define NACC (3 * NCLS)        // 57 accumulators: S | TP | N
#define ALPHA_C 0.7f
#define BETA_C 0.3f
#define EPS_C 1e-7f
#define L2E 1.44269504088896f

// R6: R5's counters showed the latency-bound signature (hbm 12%, VALU 6%,
// occupancy 18%, VGPR=72 vs ~115 live values -> allocator contortions).
// Restructure for maximal TLP and tiny register pressure:
//  - 1 pixel/thread, scalar dword loads (still 256 B/wave/class coalesced):
//    live set ~30 VGPR -> __launch_bounds__(256,8) -> 32 waves/CU capacity.
//  - grid 2048 blocks (8 resident/CU) vs R5's 512 (2/CU).
//  - S, TP, N all via 64-copy LDS float bins [57][64], copy = tid&63:
//    distinct addresses within a wave, banks 2-way aliased only (free).
//  - target prob selected in-register from e[c] (no gather load, one less exp).
//  - fused ticket tail kept from R5 (deterministic ordered sums per slice).
__global__ __launch_bounds__(256, 8) void ftl_fused(
    const float* __restrict__ x,    // [B, C, H, W]
    const int* __restrict__ tgt,    // [B, H, W]
    float* __restrict__ part,       // [NB*PB][NACC]
    int* __restrict__ counter,      // zeroed by hipMemsetAsync pre-launch
    float* __restrict__ out) {
  const int b = blockIdx.x / PB;
  const int blk = blockIdx.x % PB;
  const int tid = threadIdx.x;

  __shared__ float bins[NACC][NCOPY];
  float* bp = &bins[0][0];
  for (int i = tid; i < NACC * NCOPY; i += 256) bp[i] = 0.f;
  __syncthreads();

  const float* xb = x + (size_t)b * NCLS * HWPIX;
  const int* tb = tgt + (size_t)b * HWPIX;
  const int cp = tid & (NCOPY - 1);
  const int p0 = blk * (256 * NITER);

  for (int it = 0; it < NITER; ++it) {
    const int pix = p0 + it * 256 + tid;
    const int t = tb[pix];
    float e[NCLS];
    float s = 0.f;
#pragma unroll
    for (int c = 0; c < NCLS; ++c) {
      e[c] = __builtin_amdgcn_exp2f(xb[(size_t)c * HWPIX + pix] * L2E);
      s += e[c];
    }
    const float inv = __builtin_amdgcn_rcpf(s);
    float pt = 0.f;
#pragma unroll
    for (int c = 0; c < NCLS; ++c) {
      const float p = e[c] * inv;
      atomicAdd(&bins[c][cp], p);
      pt = (t == c) ? p : pt;   // in-register select of the target prob
    }
    atomicAdd(&bins[NCLS + t][cp], pt);
    atomicAdd(&bins[2 * NCLS + t][cp], 1.f);
  }
  __syncthreads();

  // Block epilogue: 4 lanes per accumulator sum the 64 copies, pairwise shfl.
  float* myPart = part + (size_t)blockIdx.x * NACC;
  if (tid < NACC * 4) {
    const int a = tid >> 2, qd = tid & 3;
    float v = 0.f;
#pragma unroll
    for (int i = 0; i < NCOPY / 4; ++i) v += bins[a][qd * (NCOPY / 4) + i];
    v += __shfl_down(v, 1);
    v += __shfl_down(v, 2);
    if (qd == 0) myPart[a] = v;
  }

  // ---- device-scope ticket; last block finalizes ----
  __syncthreads();  // partial stores drained before the fence/ticket
  __shared__ int lastFlag;
  if (tid == 0) {
    __threadfence();  // release this block's slice
    lastFlag = (atomicAdd(counter, 1) == NB * PB - 1);
  }
  __syncthreads();
  if (!lastFlag) return;
  __threadfence();    // acquire all slices

  __shared__ float fin[NB * NACC];  // 456 sums
  for (int pr = tid; pr < NB * NACC; pr += 256) {
    const int bb = pr / NACC, aa = pr % NACC;
    const float* q = part + (size_t)bb * PB * NACC + aa;
    float v = 0.f;
#pragma unroll 8
    for (int p = 0; p < PB; ++p) v += q[(size_t)p * NACC];  // independent loads
    fin[pr] = v;
  }
  __syncthreads();

  float v = 0.f;
  if (tid < NB * NCLS) {
    const int bb = tid / NCLS, c = tid % NCLS;
    const float S = fin[bb * NACC + c];
    const float TP = fin[bb * NACC + NCLS + c];
    const float Nc = fin[bb * NACC + 2 * NCLS + c];
    const float FPv = S - TP;
    const float FNv = Nc - TP;
    const float tv = (TP + EPS_C) / (TP + ALPHA_C * FNv + BETA_C * FPv + EPS_C);
    v = 1.0f - tv;  // GAMMA == 1.0
  }
  for (int off = 32; off; off >>= 1) v += __shfl_down(v, off);
  __shared__ float wsum[4];
  if ((tid & 63) == 0) wsum[tid >> 6] = v;
  __syncthreads();
  if (tid == 0) out[0] = (wsum[0] + wsum[1] + wsum[2] + wsum[3]) / (float)NB;
}

extern "C" void kernel_launch(void* const* d_in, const int* in_sizes, int n_in,
                              void* d_out, int out_size, void* d_ws, size_t ws_size,
                              hipStream_t stream) {
  const float* x = (const float*)d_in[0];
  const int* tgt = (const int*)d_in[1];
  float* out = (float*)d_out;
  float* part = (float*)d_ws;
  int* counter = (int*)(part + (size_t)NB * PB * NACC);  // after partials

  hipMemsetAsync(counter, 0, sizeof(int), stream);  // graph-capturable
  ftl_fused<<<NB * PB, 256, 0, stream>>>(x, tgt, part, counter, out);
}

// Round 7
// 111.753 us; speedup vs baseline: 2.3067x; 2.3067x over previous
//
#include <hip/hip_runtime.h>

#define NCLS 19
#define HWPIX (512 * 512)
#define NB 8
#define PB 256                 // blocks per image
#define CH 4                   // chunks per block
#define CP 256                 // pixels per chunk (== blockDim)
#define NCOPY 64               // LDS histogram copies for TP/N
#define NACC (3 * NCLS)        // 57: S | TP | N
#define ALPHA_C 0.7f
#define BETA_C 0.3f
#define EPS_C 1e-7f
#define L2E 1.44269504088896f

// R7: the read path, not VALU/TLP/regs, is the invariant bottleneck
// (~3.4 TB/s logical across R0-R6's wildly different shapes). Switch the
// memory engine to global_load_lds DMA staging (16 B/lane, no dest VGPRs,
// deep vmcnt queue) -- the documented gfx950 staging lever. Per chunk each
// block DMAs a 19 KB class-tile + 1 KB targets to LDS with 20 wave-instrs,
// barriers, computes softmax from LDS (2-way bank reads are free).
// S in regs; TP/N via 2 LDS atomics/pixel into 64-copy bins (R4-proven rate;
// R6's failure was 21/pixel + VGPR starvation, both avoided). Fused ticket
// tail kept from R5/R6.
__device__ __forceinline__ void g2lds16(const void* g, void* l) {
  __builtin_amdgcn_global_load_lds(
      (const __attribute__((address_space(1))) void*)g,
      (__attribute__((address_space(3))) void*)l, 16, 0, 0);
}

__global__ __launch_bounds__(256, 5) void ftl_fused(
    const float* __restrict__ x,    // [B, C, H, W]
    const int* __restrict__ tgt,    // [B, H, W]
    float* __restrict__ part,       // [NB*PB][NACC]
    int* __restrict__ counter,      // zeroed by hipMemsetAsync pre-launch
    float* __restrict__ out) {
  const int b = blockIdx.x / PB;
  const int blk = blockIdx.x % PB;
  const int tid = threadIdx.x;
  const int wv = tid >> 6, ln = tid & 63;

  __shared__ float xls[NCLS * CP];        // 19456 B staged logits tile
  __shared__ int tls[CP];                 // 1024 B staged targets
  __shared__ float bins[2 * NCLS][NCOPY]; // 9728 B TP|N histogram copies
  __shared__ float sS[NCLS];
  __shared__ float wsum[4];
  __shared__ int lastFlag;

  for (int i = tid; i < 2 * NCLS * NCOPY; i += 256) (&bins[0][0])[i] = 0.f;
  if (tid < NCLS) sS[tid] = 0.f;

  const float* xb = x + (size_t)b * NCLS * HWPIX;
  const int* tb = tgt + (size_t)b * HWPIX;
  const int cp = tid & (NCOPY - 1);

  float S[NCLS];
#pragma unroll
  for (int c = 0; c < NCLS; ++c) S[c] = 0.f;
  float TPl = 0.f;  // unused dummy to keep symmetry (removed by compiler)
  (void)TPl;

  __syncthreads();  // bins/sS init visible before first compute

  for (int ch = 0; ch < CH; ++ch) {
    const int pixbase = (blk * CH + ch) * CP;
    // ---- stage: 20 rows, wave w takes rows 5w..5w+4 (row 19 = targets) ----
#pragma unroll
    for (int r = 0; r < 5; ++r) {
      const int row = wv * 5 + r;
      if (row < NCLS) {
        g2lds16(xb + (size_t)row * HWPIX + pixbase + ln * 4, &xls[row * CP]);
      } else {  // row == 19, only wave 3 hits this
        g2lds16(tb + pixbase + ln * 4, &tls[0]);
      }
    }
    __syncthreads();  // DMAs drained (vmcnt) + all waves ready

    // ---- compute from LDS: thread tid owns pixel pixbase+tid ----
    const int t = tls[tid];
    float s = 0.f;
#pragma unroll
    for (int c = 0; c < NCLS; ++c)
      s += __builtin_amdgcn_exp2f(xls[c * CP + tid] * L2E);
    const float inv = __builtin_amdgcn_rcpf(s);
    float pt = 0.f;
#pragma unroll
    for (int c = 0; c < NCLS; ++c) {
      const float p = __builtin_amdgcn_exp2f(xls[c * CP + tid] * L2E) * inv;
      S[c] += p;
      pt = (t == c) ? p : pt;  // in-register select of target prob
    }
    atomicAdd(&bins[t][cp], pt);
    atomicAdd(&bins[NCLS + t][cp], 1.f);
    __syncthreads();  // compute done before next stage overwrites the tile
  }

  // ---- block epilogue ----
  // S: wave butterfly then wave-leader merge in LDS.
#pragma unroll
  for (int c = 0; c < NCLS; ++c) {
    float v = S[c];
    for (int off = 32; off; off >>= 1) v += __shfl_down(v, off);
    if (ln == 0) atomicAdd(&sS[c], v);
  }
  __syncthreads();
  float* myPart = part + (size_t)blockIdx.x * NACC;
  if (tid < NCLS) myPart[tid] = sS[tid];
  if (tid < 2 * NCLS * 4) {  // TP|N: 4 lanes per bin row sum 64 copies
    const int a = tid >> 2, qd = tid & 3;
    float v = 0.f;
#pragma unroll
    for (int i = 0; i < NCOPY / 4; ++i) v += bins[a][qd * (NCOPY / 4) + i];
    v += __shfl_down(v, 1);
    v += __shfl_down(v, 2);
    if (qd == 0) myPart[NCLS + a] = v;
  }

  // ---- device-scope ticket; last block finalizes ----
  __syncthreads();  // partial stores drained before fence/ticket
  if (tid == 0) {
    __threadfence();  // release this block's slice
    lastFlag = (atomicAdd(counter, 1) == NB * PB - 1);
  }
  __syncthreads();
  if (!lastFlag) return;
  __threadfence();    // acquire all slices

  __shared__ float fin[NB * NACC];  // 456 sums
  for (int pr = tid; pr < NB * NACC; pr += 256) {
    const int bb = pr / NACC, aa = pr % NACC;
    const float* q = part + (size_t)bb * PB * NACC + aa;
    float v = 0.f;
#pragma unroll 8
    for (int p = 0; p < PB; ++p) v += q[(size_t)p * NACC];  // independent loads
    fin[pr] = v;
  }
  __syncthreads();

  float v = 0.f;
  if (tid < NB * NCLS) {
    const int bb = tid / NCLS, c = tid % NCLS;
    const float Sv = fin[bb * NACC + c];
    const float TPv = fin[bb * NACC + NCLS + c];
    const float Ncv = fin[bb * NACC + 2 * NCLS + c];
    const float FPv = Sv - TPv;
    const float FNv = Ncv - TPv;
    const float tv = (TPv + EPS_C) / (TPv + ALPHA_C * FNv + BETA_C * FPv + EPS_C);
    v = 1.0f - tv;  // GAMMA == 1.0
  }
  for (int off = 32; off; off >>= 1) v += __shfl_down(v, off);
  if ((tid & 63) == 0) wsum[tid >> 6] = v;
  __syncthreads();
  if (tid == 0) out[0] = (wsum[0] + wsum[1] + wsum[2] + wsum[3]) / (float)NB;
}

extern "C" void kernel_launch(void* const* d_in, const int* in_sizes, int n_in,
                              void* d_out, int out_size, void* d_ws, size_t ws_size,
                              hipStream_t stream) {
  const float* x = (const float*)d_in[0];
  const int* tgt = (const int*)d_in[1];
  float* out = (float*)d_out;
  float* part = (float*)d_ws;
  int* counter = (int*)(part + (size_t)NB * PB * NACC);  // after partials

  hipMemsetAsync(counter, 0, sizeof(int), stream);  // graph-capturable
  ftl_fused<<<NB * PB, 256, 0, stream>>>(x, tgt, part, counter, out);
}

// Round 8
// 92.013 us; speedup vs baseline: 2.8016x; 1.2145x over previous
//
#include <hip/hip_runtime.h>

#define NCLS 19
#define HWPIX (512 * 512)
#define NB 8
#define PB 128                 // blocks per image
#define CH 8                   // chunks per block
#define CP 256                 // pixels per chunk (== blockDim)
#define NCOPY 64               // LDS histogram copies for TP/N
#define NACC (3 * NCLS)        // 57: S | TP | N
#define ALPHA_C 0.7f
#define BETA_C 0.3f
#define EPS_C 1e-7f
#define L2E 1.44269504088896f

// R8: R7's DMA engine + the schedule it was missing (T3/T4: counted vmcnt,
// never drain in-loop). Double-buffered LDS staging: issue chunk k+1's 5
// DMAs/wave, s_waitcnt vmcnt(5) (chunk k complete, k+1 still in flight),
// raw s_barrier, compute chunk k from LDS, barrier, swap. Prefetch latency
// hides under compute; ~60 KB DMA in flight per CU (3 blocks) vs ~9 KB
// Little's-law requirement. R7's exposed ~900cy/chunk drain is gone.
// WAR: stage into buf[(ch+1)&1] only happens after the end-barrier of the
// iteration that read it. ds_read results are consumed (S[c]+=) before
// barrier arrival, so compiler-inserted lgkmcnt waits already order reads
// vs buffer reuse. Bins/epilogue/ticket identical to R7 (proven correct).
__device__ __forceinline__ void g2lds16(const void* g, void* l) {
  __builtin_amdgcn_global_load_lds(
      (const __attribute__((address_space(1))) void*)g,
      (__attribute__((address_space(3))) void*)l, 16, 0, 0);
}

__global__ __launch_bounds__(256, 3) void ftl_fused(
    const float* __restrict__ x,    // [B, C, H, W]
    const int* __restrict__ tgt,    // [B, H, W]
    float* __restrict__ part,       // [NB*PB][NACC]
    int* __restrict__ counter,      // zeroed by hipMemsetAsync pre-launch
    float* __restrict__ out) {
  const int b = blockIdx.x / PB;
  const int blk = blockIdx.x % PB;
  const int tid = threadIdx.x;
  const int wv = tid >> 6, ln = tid & 63;

  __shared__ float xls[2][NCLS * CP];     // 2 x 19456 B logits tiles
  __shared__ int tls[2][CP];              // 2 x 1024 B target tiles
  __shared__ float bins[2 * NCLS][NCOPY]; // 9728 B TP|N histogram copies
  __shared__ float sS[NCLS];
  __shared__ float fin[NB * NACC];
  __shared__ float wsum[4];
  __shared__ int lastFlag;

  for (int i = tid; i < 2 * NCLS * NCOPY; i += 256) (&bins[0][0])[i] = 0.f;
  if (tid < NCLS) sS[tid] = 0.f;
  __syncthreads();  // plain barrier; nothing in the VMEM queue yet

  const float* xb = x + (size_t)b * NCLS * HWPIX;
  const int* tb = tgt + (size_t)b * HWPIX;
  const int cpidx = tid & (NCOPY - 1);

  float S[NCLS];
#pragma unroll
  for (int c = 0; c < NCLS; ++c) S[c] = 0.f;

  // Prologue: stage chunk 0 into buffer 0 (5 DMAs per wave, rows 5w..5w+4;
  // row 19 = targets). Stays in flight while we fall into the loop.
  {
    const int pixbase = (blk * CH) * CP;
#pragma unroll
    for (int r = 0; r < 5; ++r) {
      const int row = wv * 5 + r;
      if (row < NCLS)
        g2lds16(xb + (size_t)row * HWPIX + pixbase + ln * 4, &xls[0][row * CP]);
      else
        g2lds16(tb + pixbase + ln * 4, &tls[0][0]);
    }
  }

  for (int ch = 0; ch < CH; ++ch) {
    const int cur = ch & 1;
    if (ch + 1 < CH) {
      // Issue next chunk's DMAs first, then wait only for the current chunk:
      // steady state has 10 outstanding; vmcnt(5) completes the older 5.
      const int pixbase = (blk * CH + ch + 1) * CP;
      const int nxt = cur ^ 1;
#pragma unroll
      for (int r = 0; r < 5; ++r) {
        const int row = wv * 5 + r;
        if (row < NCLS)
          g2lds16(xb + (size_t)row * HWPIX + pixbase + ln * 4,
                  &xls[nxt][row * CP]);
        else
          g2lds16(tb + pixbase + ln * 4, &tls[nxt][0]);
      }
      asm volatile("s_waitcnt vmcnt(5)" ::: "memory");
    } else {
      asm volatile("s_waitcnt vmcnt(0)" ::: "memory");
    }
    __builtin_amdgcn_sched_barrier(0);
    __builtin_amdgcn_s_barrier();  // all waves' chunk-ch DMAs are complete
    __builtin_amdgcn_sched_barrier(0);

    // ---- compute chunk ch from LDS: thread owns one pixel ----
    const int t = tls[cur][tid];
    float e[NCLS];
    float s = 0.f;
#pragma unroll
    for (int c = 0; c < NCLS; ++c) {
      e[c] = __builtin_amdgcn_exp2f(xls[cur][c * CP + tid] * L2E);
      s += e[c];
    }
    const float inv = __builtin_amdgcn_rcpf(s);
    float pt = 0.f;
#pragma unroll
    for (int c = 0; c < NCLS; ++c) {
      const float p = e[c] * inv;
      S[c] += p;                 // consumes every ds_read before the barrier
      pt = (t == c) ? p : pt;    // in-register select of target prob
    }
    atomicAdd(&bins[t][cpidx], pt);
    atomicAdd(&bins[NCLS + t][cpidx], 1.f);

    __builtin_amdgcn_sched_barrier(0);
    __builtin_amdgcn_s_barrier();  // releases buf[cur] for the ch+2 stage
    __builtin_amdgcn_sched_barrier(0);
  }
  __syncthreads();  // full drain (DS atomics included) before epilogue

  // ---- block epilogue ----
#pragma unroll
  for (int c = 0; c < NCLS; ++c) {
    float v = S[c];
    for (int off = 32; off; off >>= 1) v += __shfl_down(v, off);
    if (ln == 0) atomicAdd(&sS[c], v);
  }
  __syncthreads();
  float* myPart = part + (size_t)blockIdx.x * NACC;
  if (tid < NCLS) myPart[tid] = sS[tid];
  if (tid < 2 * NCLS * 4) {  // TP|N: 4 lanes per row sum the 64 copies
    const int a = tid >> 2, qd = tid & 3;
    float v = 0.f;
#pragma unroll
    for (int i = 0; i < NCOPY / 4; ++i) v += bins[a][qd * (NCOPY / 4) + i];
    v += __shfl_down(v, 1);
    v += __shfl_down(v, 2);
    if (qd == 0) myPart[NCLS + a] = v;
  }

  // ---- device-scope ticket; last block finalizes ----
  __syncthreads();  // partial stores drained before fence/ticket
  if (tid == 0) {
    __threadfence();  // release this block's slice
    lastFlag = (atomicAdd(counter, 1) == NB * PB - 1);
  }
  __syncthreads();
  if (!lastFlag) return;
  __threadfence();    // acquire all slices

  for (int pr = tid; pr < NB * NACC; pr += 256) {
    const int bb = pr / NACC, aa = pr % NACC;
    const float* q = part + (size_t)bb * PB * NACC + aa;
    float v = 0.f;
#pragma unroll 8
    for (int p = 0; p < PB; ++p) v += q[(size_t)p * NACC];  // independent loads
    fin[pr] = v;
  }
  __syncthreads();

  float v = 0.f;
  if (tid < NB * NCLS) {
    const int bb = tid / NCLS, c = tid % NCLS;
    const float Sv = fin[bb * NACC + c];
    const float TPv = fin[bb * NACC + NCLS + c];
    const float Ncv = fin[bb * NACC + 2 * NCLS + c];
    const float FPv = Sv - TPv;
    const float FNv = Ncv - TPv;
    const float tv = (TPv + EPS_C) / (TPv + ALPHA_C * FNv + BETA_C * FPv + EPS_C);
    v = 1.0f - tv;  // GAMMA == 1.0
  }
  for (int off = 32; off; off >>= 1) v += __shfl_down(v, off);
  if ((tid & 63) == 0) wsum[tid >> 6] = v;
  __syncthreads();
  if (tid == 0) out[0] = (wsum[0] + wsum[1] + wsum[2] + wsum[3]) / (float)NB;
}

extern "C" void kernel_launch(void* const* d_in, const int* in_sizes, int n_in,
                              void* d_out, int out_size, void* d_ws, size_t ws_size,
                              hipStream_t stream) {
  const float* x = (const float*)d_in[0];
  const int* tgt = (const int*)d_in[1];
  float* out = (float*)d_out;
  float* part = (float*)d_ws;
  int* counter = (int*)(part + (size_t)NB * PB * NACC);  // after partials

  hipMemsetAsync(counter, 0, sizeof(int), stream);  // graph-capturable
  ftl_fused<<<NB * PB, 256, 0, stream>>>(x, tgt, part, counter, out);
}